// Round 1
// baseline (6064.334 us; speedup 1.0000x reference)
//
#include <hip/hip_runtime.h>
#include <stdint.h>

#define OUTN   200000
#define HID    128
#define NSTEP  64
#define KTOP   50
#define NBINS  1024
#define CAP    4096
#define NBLK   256
#define NTHR   512
#define NWRD   6250     // OUTN/32 bitmask words

// dot of one 128-wide f32 row with f32 vector in LDS
__device__ __forceinline__ float dot128f(const float* __restrict__ w, const float* __restrict__ h){
  const float4* w4 = (const float4*)w;
  float acc = 0.f;
  #pragma unroll
  for (int k=0;k<32;k++){
    float4 q = w4[k];
    const float* hp = h + k*4;
    acc += q.x*hp[0] + q.y*hp[1] + q.z*hp[2] + q.w*hp[3];
  }
  return acc;
}

__device__ __forceinline__ int binOf(float l, float rlo, float rsc){
  float b = (l - rlo) * rsc;
  b = fminf(fmaxf(b, 0.f), (float)(NBINS-1));
  return (int)b;
}

// ---------- block reductions (512 threads = 8 waves) ----------
__device__ __forceinline__ void blockRed5(float& mx, float& mn, float& a, float& b, float& c,
                                          int tid, float* sm /*>=48*/){
  #pragma unroll
  for (int o=32;o;o>>=1){
    mx=fmaxf(mx,__shfl_xor(mx,o)); mn=fminf(mn,__shfl_xor(mn,o));
    a+=__shfl_xor(a,o); b+=__shfl_xor(b,o); c+=__shfl_xor(c,o);
  }
  __syncthreads();
  if ((tid&63)==0){ int w=tid>>6; sm[w*5+0]=mx; sm[w*5+1]=mn; sm[w*5+2]=a; sm[w*5+3]=b; sm[w*5+4]=c; }
  __syncthreads();
  int nw = blockDim.x>>6;
  if (tid==0){
    for (int k=1;k<nw;k++){
      sm[0]=fmaxf(sm[0],sm[k*5+0]); sm[1]=fminf(sm[1],sm[k*5+1]);
      sm[2]+=sm[k*5+2]; sm[3]+=sm[k*5+3]; sm[4]+=sm[k*5+4];
    }
  }
  __syncthreads();
  mx=sm[0]; mn=sm[1]; a=sm[2]; b=sm[3]; c=sm[4];
}

__device__ __forceinline__ void blockRedPair(float& p, int& i, int tid, float* smp, int* smi){
  __syncthreads();
  #pragma unroll
  for (int o=32;o;o>>=1){
    float p2=__shfl_xor(p,o); int i2=__shfl_xor(i,o);
    if (p2>p || (p2==p && i2<i)){ p=p2; i=i2; }
  }
  if ((tid&63)==0){ smp[tid>>6]=p; smi[tid>>6]=i; }
  __syncthreads();
  if (tid==0){
    for (int k=1;k<8;k++){
      if (smp[k]>smp[0] || (smp[k]==smp[0] && smi[k]<smi[0])){ smp[0]=smp[k]; smi[0]=smi[k]; }
    }
  }
  __syncthreads();
  p=smp[0]; i=smi[0];
}

__device__ __forceinline__ int blockRedSum(int v, int tid, int* smi){
  __syncthreads();
  #pragma unroll
  for (int o=32;o;o>>=1) v += __shfl_xor(v,o);
  if ((tid&63)==0) smi[tid>>6]=v;
  __syncthreads();
  if (tid==0){ int s=0; for(int k=0;k<8;k++) s+=smi[k]; smi[0]=s; }
  __syncthreads();
  return smi[0];
}

// highest bin bstar with count(bin>=bstar) >= K. outp[0]=bstar, outp[1]=count.
__device__ __forceinline__ void histSelect(unsigned* histL, unsigned* csum, int tid, int K, int* outp){
  int base = NBINS - 2*(tid+1);
  csum[tid] = histL[base] + histL[base+1];
  __syncthreads();
  for (int off=1; off<NTHR; off<<=1){
    unsigned add = (tid>=off) ? csum[tid-off] : 0u;
    __syncthreads();
    csum[tid] += add;
    __syncthreads();
  }
  unsigned pre = (tid==0)?0u:csum[tid-1];
  if (csum[tid] >= (unsigned)K && pre < (unsigned)K){
    unsigned run = pre; int bs = base;
    for (int b=base+1; b>=base; --b){
      run += histL[b];
      if (run >= (unsigned)K){ bs=b; break; }
    }
    outp[0]=bs; outp[1]=(int)run;
  }
  __syncthreads();
}

// ---------- grid barrier (cooperative launch; agent-scope coherence) ----------
// Monotonic counter. __threadfence() at agent scope emits the L2 writeback /
// invalidate needed across the 8 non-coherent XCD L2s on gfx950; the
// s_waitcnt vmcnt(0) the compiler inserts before s_barrier guarantees all
// waves' stores have reached L2 before thread 0 flushes it.
__device__ __forceinline__ void gsync(unsigned* bar, unsigned target){
  __syncthreads();
  if (threadIdx.x==0){
    __threadfence();   // release: writeback dirty L2
    __hip_atomic_fetch_add(bar, 1u, __ATOMIC_RELAXED, __HIP_MEMORY_SCOPE_AGENT);
    unsigned v;
    do {
      __builtin_amdgcn_s_sleep(4);
      v = __hip_atomic_load(bar, __ATOMIC_RELAXED, __HIP_MEMORY_SCOPE_AGENT);
    } while (v < target);
    __threadfence();   // acquire: invalidate L1/L2
  }
  __syncthreads();
}

// ---------- init kernel (also resets the grid-barrier counter) ----------
extern "C" __global__ void k_init(const int* __restrict__ x,
                                  const float* __restrict__ b_ih, const float* __restrict__ b_hh,
                                  unsigned* mask_bits, unsigned* inx_bits, unsigned* hist_g,
                                  unsigned* gcount, float* rparams, float* h_ws, float* c_ws,
                                  unsigned* bar)
{
  int tid = threadIdx.x;  // single block, 1024 threads
  for (int i=tid;i<NWRD;i+=1024){ mask_bits[i]=0xFFFFFFFFu; inx_bits[i]=0u; }
  for (int i=tid;i<NBINS;i+=1024) hist_g[i]=0u;
  if (tid==0){ *gcount=0u; rparams[0]=0.f; rparams[1]=0.f; *bar=0u; }
  if (tid<HID){
    // state after reference step 0 (emb=0, h=c=0)
    float ig=b_ih[tid]       +b_hh[tid];
    float gg=b_ih[tid+2*HID] +b_hh[tid+2*HID];
    float og=b_ih[tid+3*HID] +b_hh[tid+3*HID];
    float si=1.f/(1.f+expf(-ig)), so=1.f/(1.f+expf(-og));
    float cn=si*tanhf(gg);
    c_ws[tid]=cn; h_ws[tid]=so*tanhf(cn);
  }
  __syncthreads();
  if (tid<200){
    int v = x[tid]-1;                       // 1-indexed items
    if (v>=0 && v<OUTN) atomicOr(&inx_bits[v>>5], 1u<<(v&31));
  }
}

// ---------- fused persistent kernel: all 64 steps in one dispatch ----------
struct FusedP {
  const float* emb;  const float* Wih;  const float* Whh;
  const float* bih;  const float* bhh;  const float* Wout; const float* bout;
  float* out;
  float* l_ws; float* partials;
  unsigned* mask_bits; unsigned* inx_bits; unsigned* hist_g;
  unsigned* cand; unsigned* gcount; float* rparams;
  float* h_ws; float* c_ws; unsigned* bar;
};

extern "C" __global__ void __launch_bounds__(NTHR) k_fused(FusedP p)
{
  __shared__ float    h_l[HID];
  __shared__ float    emb_l[HID];
  __shared__ float    gates[4*HID];
  __shared__ unsigned hl[NBINS];
  __shared__ unsigned csum[NTHR];
  __shared__ float    smf[48];
  __shared__ float    smp[8];
  __shared__ int      smi[8];
  __shared__ int      s_sel[2];
  __shared__ int      s_nc, s_cnt;

  const int tid=threadIdx.x, bid=blockIdx.x;
  // balanced contiguous chunks: blocks 0..63 take 782 rows, rest 781
  const int start = bid*781 + (bid<64 ? bid : 64);
  const int cnt   = 781 + (bid<64 ? 1 : 0);
  unsigned barT = 0;

  for (int t=0; t<NSTEP; ++t){
    // ---------------- phase L: logits + stats + histogram ----------------
    if (tid<HID) h_l[tid]=p.h_ws[tid];
    for (int i=tid;i<NBINS;i+=NTHR) hl[i]=0u;
    float rlo = p.rparams[0], rsc = p.rparams[1];   // uniform across grid
    __syncthreads();
    float mx=-3e38f, mn=3e38f, se=0.f, sl=0.f, sl2=0.f;
    for (int j=tid;j<cnt;j+=NTHR){
      int row = start+j;
      float l = dot128f(p.Wout+(size_t)row*HID, h_l) + p.bout[row];
      p.l_ws[row]=l;
      se += expf(l)-1.f; sl += l; sl2 += l*l;
      if ((p.mask_bits[row>>5]>>(row&31))&1u){
        mx=fmaxf(mx,l); mn=fminf(mn,l);
        if (rsc>0.f) atomicAdd(&hl[binOf(l,rlo,rsc)],1u);
      }
    }
    blockRed5(mx,mn,se,sl,sl2,tid,smf);
    if (tid==0){ float* q=&p.partials[bid*8]; q[0]=mx;q[1]=mn;q[2]=se;q[3]=sl;q[4]=sl2; }
    if (rsc>0.f){
      for (int i=tid;i<NBINS;i+=NTHR){ unsigned v=hl[i]; if (v) atomicAdd(&p.hist_g[i],v); }
    }
    barT += NBLK; gsync(p.bar, barT);

    // ---- bootstrap (t==0 or degenerate rparams): build histogram grid-wide ----
    // Every block reduces the SAME partials in the SAME order -> identical
    // rlo/rsc in all blocks without any extra global round-trip.
    if (!(rsc>0.f)){
      float bmx=-3e38f,bmn=3e38f,bse=0.f,bsl=0.f,bsl2=0.f;
      if (tid<NBLK){ const float* q=&p.partials[tid*8]; bmx=q[0];bmn=q[1];bse=q[2];bsl=q[3];bsl2=q[4]; }
      blockRed5(bmx,bmn,bse,bsl,bsl2,tid,smf);
      float mean=bsl/2.0e5f, var=bsl2/2.0e5f-mean*mean, sg=sqrtf(fmaxf(var,0.f));
      rlo = bmx-24.f*sg; rsc = (sg>0.f)?((float)NBINS/(32.f*sg)):0.f;
      if (rsc>0.f){
        for (int i=tid;i<NBINS;i+=NTHR) hl[i]=0u;
        __syncthreads();
        for (int j=tid;j<cnt;j+=NTHR){
          int row=start+j;
          if ((p.mask_bits[row>>5]>>(row&31))&1u)
            atomicAdd(&hl[binOf(p.l_ws[row],rlo,rsc)],1u);
        }
        __syncthreads();
        for (int i=tid;i<NBINS;i+=NTHR){ unsigned v=hl[i]; if (v) atomicAdd(&p.hist_g[i],v); }
      }
      barT += NBLK; gsync(p.bar, barT);
    }

    // ---------------- phase E: emit probs + collect candidates ----------------
    float gmx=-3e38f,gmn=3e38f,gse=0.f,gsl=0.f,gsl2=0.f;
    if (tid<NBLK){ const float* q=&p.partials[tid*8]; gmx=q[0];gmn=q[1];gse=q[2];gsl=q[3];gsl2=q[4]; }
    for (int i=tid;i<NBINS;i+=NTHR) hl[i]=p.hist_g[i];
    if (tid==0){ s_sel[0]=NBINS; s_sel[1]=0x7fffffff; }   // defaults if hist empty
    blockRed5(gmx,gmn,gse,gsl,gsl2,tid,smf);
    const float invS = 1.f/(2.0e5f + gse);
    histSelect(hl,csum,tid,KTOP,s_sel);
    const int  bstar  = s_sel[0];
    const int  bcnt   = s_sel[1];
    const bool doComp = (bcnt<=CAP) && (rsc>0.f);
    float* orow = p.out + 2*NSTEP + (size_t)t*OUTN;
    for (int j=tid;j<cnt;j+=NTHR){
      int row = start+j;
      float l = p.l_ws[row];
      bool m = (p.mask_bits[row>>5]>>(row&31))&1u;
      orow[row] = m ? expf(l)*invS : 0.f;
      if (doComp && m && binOf(l,rlo,rsc)>=bstar){
        unsigned pos = atomicAdd(p.gcount,1u);
        if (pos<CAP) p.cand[pos]=(unsigned)row;
      }
    }
    barT += NBLK; gsync(p.bar, barT);

    // ---------------- phase S: selection + LSTM (block 0); hist clear (block 1) ----------------
    if (bid==0){
      int nc = doComp ? (int)(*p.gcount) : 0;
      bool ok = doComp && nc>=KTOP && nc<=CAP;

      if (!ok){
        if (gmn >= gmx){
          // all masked logits tied: top-K = lowest-index masked rows
          if (tid==0){
            int c=0;
            for (int i=0;i<OUTN && c<KTOP;i++)
              if ((p.mask_bits[i>>5]>>(i&31))&1u) p.cand[c++]=(unsigned)i;
            s_nc=c;
          }
        } else {
          // exact histogram over [gmn, gmx]
          for (int i=tid;i<NBINS;i+=NTHR) hl[i]=0u;
          __syncthreads();
          const float sc2 = (float)NBINS/(gmx-gmn);
          for (int i=tid;i<OUTN;i+=NTHR)
            if ((p.mask_bits[i>>5]>>(i&31))&1u)
              atomicAdd(&hl[binOf(p.l_ws[i],gmn,sc2)],1u);
          __syncthreads();
          histSelect(hl,csum,tid,KTOP,s_sel);
          int b2=s_sel[0], c2=s_sel[1];
          if (c2<=CAP){
            if (tid==0) s_cnt=0;
            __syncthreads();
            for (int i=tid;i<OUTN;i+=NTHR){
              if ((p.mask_bits[i>>5]>>(i&31))&1u && binOf(p.l_ws[i],gmn,sc2)>=b2){
                int q=atomicAdd(&s_cnt,1);
                if (q<CAP) p.cand[q]=(unsigned)i;
              }
            }
            __syncthreads();
            if (tid==0) s_nc = (s_cnt<CAP ? s_cnt : CAP);
          } else {
            // massive ties above threshold: index-order collect (stable tie-break)
            if (tid==0){
              int c=0;
              for (int i=0;i<OUTN && c<KTOP;i++)
                if (((p.mask_bits[i>>5]>>(i&31))&1u) && binOf(p.l_ws[i],gmn,sc2)>=b2) p.cand[c++]=(unsigned)i;
              s_nc=c;
            }
          }
        }
        __syncthreads();
        nc = s_nc;
      }

      // selection ordered by (l desc, idx asc)
      float bp=-3.4e38f; int bi=0x7fffffff;
      float hp=-3.4e38f; int hidx=0x7fffffff;
      for (int j=tid;j<nc;j+=NTHR){
        int idx=(int)p.cand[j];
        float l=p.l_ws[idx];
        if (l>bp || (l==bp && idx<bi)){ bp=l; bi=idx; }
        if (((p.inx_bits[idx>>5]>>(idx&31))&1u) && (l>hp || (l==hp && idx<hidx))){ hp=l; hidx=idx; }
      }
      blockRedPair(bp,bi,tid,smp,smi);
      blockRedPair(hp,hidx,tid,smp,smi);
      int a, fb;
      if (hidx != 0x7fffffff){
        int better=0;
        for (int j=tid;j<nc;j+=NTHR){
          int idx=(int)p.cand[j];
          float l=p.l_ws[idx];
          better += (l>hp || (l==hp && idx<hidx)) ? 1 : 0;
        }
        better = blockRedSum(better,tid,smi);
        if (better < KTOP){ a=hidx; fb=1; } else { a=bi; fb=-1; }
      } else { a=bi; fb=-1; }
      if (a<0 || a>=OUTN) a=0;      // safety clamp

      if (tid==0){
        p.out[t]       = (float)a;
        p.out[NSTEP+t] = (float)fb;
        atomicAnd(&p.mask_bits[a>>5], ~(1u<<(a&31)));
      }

      // LSTM update (h_l still holds this step's h from phase L)
      if (tid<HID) emb_l[tid]=p.emb[(size_t)a*HID+tid] * (float)fb;
      __syncthreads();
      float g = dot128f(p.Wih+(size_t)tid*HID, emb_l) + dot128f(p.Whh+(size_t)tid*HID, h_l)
              + p.bih[tid] + p.bhh[tid];
      gates[tid]=g;
      __syncthreads();
      if (tid<HID){
        float ig=gates[tid], fg=gates[tid+HID], gg=gates[tid+2*HID], og=gates[tid+3*HID];
        float si=1.f/(1.f+expf(-ig)), sf=1.f/(1.f+expf(-fg)), so=1.f/(1.f+expf(-og));
        float cn=sf*p.c_ws[tid]+si*tanhf(gg);
        float hn=so*tanhf(cn);
        p.c_ws[tid]=cn; p.h_ws[tid]=hn;
      }

      if (tid==0){
        *p.gcount=0u;
        float mean=gsl/2.0e5f;
        float var =gsl2/2.0e5f - mean*mean;
        float sg  =sqrtf(fmaxf(var,0.f));
        p.rparams[0]=gmx-24.f*sg;
        p.rparams[1]=(sg>0.f)?((float)NBINS/(32.f*sg)):0.f;
      }
    } else if (bid==1){
      for (int i=tid;i<NBINS;i+=NTHR) p.hist_g[i]=0u;
    }
    barT += NBLK; gsync(p.bar, barT);
  }
}

// ---------- host ----------
extern "C" void kernel_launch(void* const* d_in, const int* in_sizes, int n_in,
                              void* d_out, int out_size, void* d_ws, size_t ws_size,
                              hipStream_t stream)
{
  const int*   x    = (const int*)d_in[0];
  const float* emb  = (const float*)d_in[1];
  const float* Wih  = (const float*)d_in[2];
  const float* Whh  = (const float*)d_in[3];
  const float* bih  = (const float*)d_in[4];
  const float* bhh  = (const float*)d_in[5];
  const float* Wout = (const float*)d_in[6];
  const float* bout = (const float*)d_in[7];
  float* out = (float*)d_out;

  char* ws = (char*)d_ws;
  float*    l_ws      = (float*)(ws + 0);         // 800000 B
  float*    partials  = (float*)(ws + 800000);    // 8192
  unsigned* mask_bits = (unsigned*)(ws + 808192); // 25000 (+pad)
  unsigned* inx_bits  = (unsigned*)(ws + 833280); // 25000 (+pad)
  unsigned* hist_g    = (unsigned*)(ws + 858368); // 4096
  unsigned* cand      = (unsigned*)(ws + 862464); // 16384
  unsigned* gcount    = (unsigned*)(ws + 878848); // 4
  unsigned* bar       = (unsigned*)(ws + 878976); // 4 (inside gcount padding)
  float*    rparams   = (float*)(ws + 879104);    // 8 (pad 256)
  float*    h_ws      = (float*)(ws + 879360);    // 512
  float*    c_ws      = (float*)(ws + 879872);    // 512 -> total 880384 B

  hipLaunchKernelGGL(k_init, dim3(1), dim3(1024), 0, stream,
                     x, bih, bhh, mask_bits, inx_bits, hist_g, gcount, rparams, h_ws, c_ws, bar);

  FusedP p;
  p.emb=emb; p.Wih=Wih; p.Whh=Whh; p.bih=bih; p.bhh=bhh; p.Wout=Wout; p.bout=bout;
  p.out=out; p.l_ws=l_ws; p.partials=partials;
  p.mask_bits=mask_bits; p.inx_bits=inx_bits; p.hist_g=hist_g;
  p.cand=cand; p.gcount=gcount; p.rparams=rparams;
  p.h_ws=h_ws; p.c_ws=c_ws; p.bar=bar;

  void* args[] = { &p };
  hipLaunchCooperativeKernel((const void*)k_fused, dim3(NBLK), dim3(NTHR), args, 0, stream);
}

// Round 2
// 4264.566 us; speedup vs baseline: 1.4220x; 1.4220x over previous
//
#include <hip/hip_runtime.h>
#include <stdint.h>

#define OUTN   200000
#define HID    128
#define NSTEP  64
#define KTOP   50
#define NBINS  1024
#define CAP    4096
#define NBLK   256
#define NTHR   512
#define NWRD   6250     // OUTN/32 bitmask words

// ---------- agent-scope (cross-XCD coherent, cache-bypassing) accessors ----------
// All cross-block RW data goes through these (or device-scope atomic RMW).
// Read-only inputs use normal cached loads -> L2 keeps W_out across steps
// because we never issue L2 invalidates.
__device__ __forceinline__ float    gldf(const float* p){ return __hip_atomic_load(p, __ATOMIC_RELAXED, __HIP_MEMORY_SCOPE_AGENT); }
__device__ __forceinline__ void     gstf(float* p, float v){ __hip_atomic_store(p, v, __ATOMIC_RELAXED, __HIP_MEMORY_SCOPE_AGENT); }
__device__ __forceinline__ unsigned gldu(const unsigned* p){ return __hip_atomic_load(p, __ATOMIC_RELAXED, __HIP_MEMORY_SCOPE_AGENT); }
__device__ __forceinline__ void     gstu(unsigned* p, unsigned v){ __hip_atomic_store(p, v, __ATOMIC_RELAXED, __HIP_MEMORY_SCOPE_AGENT); }

// dot of one 128-wide f32 row with f32 vector in LDS
__device__ __forceinline__ float dot128f(const float* __restrict__ w, const float* __restrict__ h){
  const float4* w4 = (const float4*)w;
  float acc = 0.f;
  #pragma unroll
  for (int k=0;k<32;k++){
    float4 q = w4[k];
    const float* hp = h + k*4;
    acc += q.x*hp[0] + q.y*hp[1] + q.z*hp[2] + q.w*hp[3];
  }
  return acc;
}

__device__ __forceinline__ int binOf(float l, float rlo, float rsc){
  float b = (l - rlo) * rsc;
  b = fminf(fmaxf(b, 0.f), (float)(NBINS-1));
  return (int)b;
}

// ---------- block reductions (512 threads = 8 waves) ----------
__device__ __forceinline__ void blockRed5(float& mx, float& mn, float& a, float& b, float& c,
                                          int tid, float* sm /*>=48*/){
  #pragma unroll
  for (int o=32;o;o>>=1){
    mx=fmaxf(mx,__shfl_xor(mx,o)); mn=fminf(mn,__shfl_xor(mn,o));
    a+=__shfl_xor(a,o); b+=__shfl_xor(b,o); c+=__shfl_xor(c,o);
  }
  __syncthreads();
  if ((tid&63)==0){ int w=tid>>6; sm[w*5+0]=mx; sm[w*5+1]=mn; sm[w*5+2]=a; sm[w*5+3]=b; sm[w*5+4]=c; }
  __syncthreads();
  int nw = blockDim.x>>6;
  if (tid==0){
    for (int k=1;k<nw;k++){
      sm[0]=fmaxf(sm[0],sm[k*5+0]); sm[1]=fminf(sm[1],sm[k*5+1]);
      sm[2]+=sm[k*5+2]; sm[3]+=sm[k*5+3]; sm[4]+=sm[k*5+4];
    }
  }
  __syncthreads();
  mx=sm[0]; mn=sm[1]; a=sm[2]; b=sm[3]; c=sm[4];
}

__device__ __forceinline__ void blockRedPair(float& p, int& i, int tid, float* smp, int* smi){
  __syncthreads();
  #pragma unroll
  for (int o=32;o;o>>=1){
    float p2=__shfl_xor(p,o); int i2=__shfl_xor(i,o);
    if (p2>p || (p2==p && i2<i)){ p=p2; i=i2; }
  }
  if ((tid&63)==0){ smp[tid>>6]=p; smi[tid>>6]=i; }
  __syncthreads();
  if (tid==0){
    for (int k=1;k<8;k++){
      if (smp[k]>smp[0] || (smp[k]==smp[0] && smi[k]<smi[0])){ smp[0]=smp[k]; smi[0]=smi[k]; }
    }
  }
  __syncthreads();
  p=smp[0]; i=smi[0];
}

__device__ __forceinline__ int blockRedSum(int v, int tid, int* smi){
  __syncthreads();
  #pragma unroll
  for (int o=32;o;o>>=1) v += __shfl_xor(v,o);
  if ((tid&63)==0) smi[tid>>6]=v;
  __syncthreads();
  if (tid==0){ int s=0; for(int k=0;k<8;k++) s+=smi[k]; smi[0]=s; }
  __syncthreads();
  return smi[0];
}

// highest bin bstar with count(bin>=bstar) >= K. outp[0]=bstar, outp[1]=count.
__device__ __forceinline__ void histSelect(unsigned* histL, unsigned* csum, int tid, int K, int* outp){
  int base = NBINS - 2*(tid+1);
  csum[tid] = histL[base] + histL[base+1];
  __syncthreads();
  for (int off=1; off<NTHR; off<<=1){
    unsigned add = (tid>=off) ? csum[tid-off] : 0u;
    __syncthreads();
    csum[tid] += add;
    __syncthreads();
  }
  unsigned pre = (tid==0)?0u:csum[tid-1];
  if (csum[tid] >= (unsigned)K && pre < (unsigned)K){
    unsigned run = pre; int bs = base;
    for (int b=base+1; b>=base; --b){
      run += histL[b];
      if (run >= (unsigned)K){ bs=b; break; }
    }
    outp[0]=bs; outp[1]=(int)run;
  }
  __syncthreads();
}

// ---------- fence-free grid barrier ----------
// All shared RW data is agent-scope (IF$-coherent) by construction, so the
// barrier needs NO cache maintenance: drain this wave's outstanding vmem
// (store-ack at the coherence point), rendezvous, bump counter, spin.
__device__ __forceinline__ void gsync(unsigned* bar, unsigned target){
  asm volatile("s_waitcnt vmcnt(0) lgkmcnt(0)" ::: "memory");
  __syncthreads();            // compiler also drains vmcnt per-wave here
  if (threadIdx.x==0){
    __hip_atomic_fetch_add(bar, 1u, __ATOMIC_RELAXED, __HIP_MEMORY_SCOPE_AGENT);
    unsigned v;
    do {
      __builtin_amdgcn_s_sleep(2);
      v = __hip_atomic_load(bar, __ATOMIC_RELAXED, __HIP_MEMORY_SCOPE_AGENT);
    } while (v < target);
  }
  __syncthreads();
  asm volatile("" ::: "memory");
}

// ---------- init kernel (also resets the grid-barrier counter) ----------
extern "C" __global__ void k_init(const int* __restrict__ x,
                                  const float* __restrict__ b_ih, const float* __restrict__ b_hh,
                                  unsigned* mask_bits, unsigned* inx_bits, unsigned* hist_g,
                                  unsigned* gcount, float* rparams, float* h_ws, float* c_ws,
                                  unsigned* bar)
{
  int tid = threadIdx.x;  // single block, 1024 threads
  for (int i=tid;i<NWRD;i+=1024){ mask_bits[i]=0xFFFFFFFFu; inx_bits[i]=0u; }
  for (int i=tid;i<NBINS;i+=1024) hist_g[i]=0u;
  if (tid==0){ *gcount=0u; rparams[0]=0.f; rparams[1]=0.f; *bar=0u; }
  if (tid<HID){
    // state after reference step 0 (emb=0, h=c=0)
    float ig=b_ih[tid]       +b_hh[tid];
    float gg=b_ih[tid+2*HID] +b_hh[tid+2*HID];
    float og=b_ih[tid+3*HID] +b_hh[tid+3*HID];
    float si=1.f/(1.f+expf(-ig)), so=1.f/(1.f+expf(-og));
    float cn=si*tanhf(gg);
    c_ws[tid]=cn; h_ws[tid]=so*tanhf(cn);
  }
  __syncthreads();
  if (tid<200){
    int v = x[tid]-1;                       // 1-indexed items
    if (v>=0 && v<OUTN) atomicOr(&inx_bits[v>>5], 1u<<(v&31));
  }
}

// ---------- fused persistent kernel: all 64 steps in one dispatch ----------
struct FusedP {
  const float* emb;  const float* Wih;  const float* Whh;
  const float* bih;  const float* bhh;  const float* Wout; const float* bout;
  float* out;
  float* l_ws; float* partials;
  unsigned* mask_bits; unsigned* inx_bits; unsigned* hist_g;
  unsigned* cand; unsigned* gcount; float* rparams;
  float* h_ws; float* c_ws; unsigned* bar;
};

extern "C" __global__ void __launch_bounds__(NTHR) k_fused(FusedP p)
{
  __shared__ float    h_l[HID];
  __shared__ float    emb_l[HID];
  __shared__ float    gates[4*HID];
  __shared__ unsigned hl[NBINS];
  __shared__ unsigned csum[NTHR];
  __shared__ float    smf[48];
  __shared__ float    smp[8];
  __shared__ int      smi[8];
  __shared__ int      s_sel[2];
  __shared__ int      s_nc, s_cnt;

  const int tid=threadIdx.x, bid=blockIdx.x;
  // balanced contiguous chunks: blocks 0..63 take 782 rows, rest 781
  const int start = bid*781 + (bid<64 ? bid : 64);
  const int cnt   = 781 + (bid<64 ? 1 : 0);
  unsigned barT = 0;

  for (int t=0; t<NSTEP; ++t){
    // ---------------- phase L: logits + stats + histogram ----------------
    if (tid<HID) h_l[tid]=gldf(&p.h_ws[tid]);
    for (int i=tid;i<NBINS;i+=NTHR) hl[i]=0u;
    float rlo = gldf(&p.rparams[0]), rsc = gldf(&p.rparams[1]);   // uniform across grid
    __syncthreads();
    float mx=-3e38f, mn=3e38f, se=0.f, sl=0.f, sl2=0.f;
    float lv0=0.f, lv1=0.f; unsigned mv0=0u, mv1=0u;   // register-carried L->E
    {
      int j = tid;
      if (j < cnt){
        int row = start+j;
        float l = dot128f(p.Wout+(size_t)row*HID, h_l) + p.bout[row];
        gstf(&p.l_ws[row], l);
        lv0 = l;
        se += expf(l)-1.f; sl += l; sl2 += l*l;
        if ((gldu(&p.mask_bits[row>>5])>>(row&31))&1u){
          mv0 = 1u;
          mx=fmaxf(mx,l); mn=fminf(mn,l);
          if (rsc>0.f) atomicAdd(&hl[binOf(l,rlo,rsc)],1u);
        }
      }
      j = tid + NTHR;
      if (j < cnt){
        int row = start+j;
        float l = dot128f(p.Wout+(size_t)row*HID, h_l) + p.bout[row];
        gstf(&p.l_ws[row], l);
        lv1 = l;
        se += expf(l)-1.f; sl += l; sl2 += l*l;
        if ((gldu(&p.mask_bits[row>>5])>>(row&31))&1u){
          mv1 = 1u;
          mx=fmaxf(mx,l); mn=fminf(mn,l);
          if (rsc>0.f) atomicAdd(&hl[binOf(l,rlo,rsc)],1u);
        }
      }
    }
    blockRed5(mx,mn,se,sl,sl2,tid,smf);
    if (tid==0){
      float* q=&p.partials[bid*8];
      gstf(q+0,mx); gstf(q+1,mn); gstf(q+2,se); gstf(q+3,sl); gstf(q+4,sl2);
    }
    if (rsc>0.f){
      for (int i=tid;i<NBINS;i+=NTHR){ unsigned v=hl[i]; if (v) atomicAdd(&p.hist_g[i],v); }
    }
    barT += NBLK; gsync(p.bar, barT);

    // ---- bootstrap (t==0 or degenerate rparams): rebuild hist grid-wide ----
    // Every block reduces the SAME partials in the SAME order -> identical
    // rlo/rsc in all blocks. Histogram rebuilt from register-carried logits.
    if (!(rsc>0.f)){
      float bmx=-3e38f,bmn=3e38f,bse=0.f,bsl=0.f,bsl2=0.f;
      if (tid<NBLK){
        const float* q=&p.partials[tid*8];
        bmx=gldf(q+0); bmn=gldf(q+1); bse=gldf(q+2); bsl=gldf(q+3); bsl2=gldf(q+4);
      }
      blockRed5(bmx,bmn,bse,bsl,bsl2,tid,smf);
      float mean=bsl/2.0e5f, var=bsl2/2.0e5f-mean*mean, sg=sqrtf(fmaxf(var,0.f));
      rlo = bmx-24.f*sg; rsc = (sg>0.f)?((float)NBINS/(32.f*sg)):0.f;
      if (rsc>0.f){
        for (int i=tid;i<NBINS;i+=NTHR) hl[i]=0u;
        __syncthreads();
        if (mv0) atomicAdd(&hl[binOf(lv0,rlo,rsc)],1u);
        if (mv1) atomicAdd(&hl[binOf(lv1,rlo,rsc)],1u);
        __syncthreads();
        for (int i=tid;i<NBINS;i+=NTHR){ unsigned v=hl[i]; if (v) atomicAdd(&p.hist_g[i],v); }
      }
      barT += NBLK; gsync(p.bar, barT);
    }

    // ---------------- phase E: emit probs + collect candidates ----------------
    float gmx=-3e38f,gmn=3e38f,gse=0.f,gsl=0.f,gsl2=0.f;
    if (tid<NBLK){
      const float* q=&p.partials[tid*8];
      gmx=gldf(q+0); gmn=gldf(q+1); gse=gldf(q+2); gsl=gldf(q+3); gsl2=gldf(q+4);
    }
    for (int i=tid;i<NBINS;i+=NTHR) hl[i]=gldu(&p.hist_g[i]);
    if (tid==0){ s_sel[0]=NBINS; s_sel[1]=0x7fffffff; }   // defaults if hist empty
    blockRed5(gmx,gmn,gse,gsl,gsl2,tid,smf);
    const float invS = 1.f/(2.0e5f + gse);
    histSelect(hl,csum,tid,KTOP,s_sel);
    const int  bstar  = s_sel[0];
    const int  bcnt   = s_sel[1];
    const bool doComp = (bcnt<=CAP) && (rsc>0.f);
    float* orow = p.out + 2*NSTEP + (size_t)t*OUTN;
    {
      int j = tid;
      if (j < cnt){
        int row = start+j;
        __builtin_nontemporal_store(mv0 ? expf(lv0)*invS : 0.f, &orow[row]);
        if (doComp && mv0 && binOf(lv0,rlo,rsc)>=bstar){
          unsigned pos = atomicAdd(p.gcount,1u);
          if (pos<CAP) gstu(&p.cand[pos],(unsigned)row);
        }
      }
      j = tid + NTHR;
      if (j < cnt){
        int row = start+j;
        __builtin_nontemporal_store(mv1 ? expf(lv1)*invS : 0.f, &orow[row]);
        if (doComp && mv1 && binOf(lv1,rlo,rsc)>=bstar){
          unsigned pos = atomicAdd(p.gcount,1u);
          if (pos<CAP) gstu(&p.cand[pos],(unsigned)row);
        }
      }
    }
    barT += NBLK; gsync(p.bar, barT);

    // ---------------- phase S: selection + LSTM (block 0); hist clear (block 1) ----------------
    if (bid==0){
      int nc = doComp ? (int)gldu(p.gcount) : 0;
      bool ok = doComp && nc>=KTOP && nc<=CAP;

      if (!ok){
        if (gmn >= gmx){
          // all masked logits tied: top-K = lowest-index masked rows
          if (tid==0){
            int c=0;
            for (int i=0;i<OUTN && c<KTOP;i++)
              if ((gldu(&p.mask_bits[i>>5])>>(i&31))&1u) gstu(&p.cand[c++],(unsigned)i);
            s_nc=c;
          }
        } else {
          // exact histogram over [gmn, gmx]
          for (int i=tid;i<NBINS;i+=NTHR) hl[i]=0u;
          __syncthreads();
          const float sc2 = (float)NBINS/(gmx-gmn);
          for (int i=tid;i<OUTN;i+=NTHR)
            if ((gldu(&p.mask_bits[i>>5])>>(i&31))&1u)
              atomicAdd(&hl[binOf(gldf(&p.l_ws[i]),gmn,sc2)],1u);
          __syncthreads();
          histSelect(hl,csum,tid,KTOP,s_sel);
          int b2=s_sel[0], c2=s_sel[1];
          if (c2<=CAP){
            if (tid==0) s_cnt=0;
            __syncthreads();
            for (int i=tid;i<OUTN;i+=NTHR){
              if ((gldu(&p.mask_bits[i>>5])>>(i&31))&1u && binOf(gldf(&p.l_ws[i]),gmn,sc2)>=b2){
                int q=atomicAdd(&s_cnt,1);
                if (q<CAP) gstu(&p.cand[q],(unsigned)i);
              }
            }
            __syncthreads();
            if (tid==0) s_nc = (s_cnt<CAP ? s_cnt : CAP);
          } else {
            // massive ties above threshold: index-order collect (stable tie-break)
            if (tid==0){
              int c=0;
              for (int i=0;i<OUTN && c<KTOP;i++)
                if (((gldu(&p.mask_bits[i>>5])>>(i&31))&1u) && binOf(gldf(&p.l_ws[i]),gmn,sc2)>=b2)
                  gstu(&p.cand[c++],(unsigned)i);
              s_nc=c;
            }
          }
        }
        __syncthreads();
        nc = s_nc;
      }

      // selection ordered by (l desc, idx asc)
      float bp=-3.4e38f; int bi=0x7fffffff;
      float hp=-3.4e38f; int hidx=0x7fffffff;
      for (int j=tid;j<nc;j+=NTHR){
        int idx=(int)gldu(&p.cand[j]);
        float l=gldf(&p.l_ws[idx]);
        if (l>bp || (l==bp && idx<bi)){ bp=l; bi=idx; }
        if (((p.inx_bits[idx>>5]>>(idx&31))&1u) && (l>hp || (l==hp && idx<hidx))){ hp=l; hidx=idx; }
      }
      blockRedPair(bp,bi,tid,smp,smi);
      blockRedPair(hp,hidx,tid,smp,smi);
      int a, fb;
      if (hidx != 0x7fffffff){
        int better=0;
        for (int j=tid;j<nc;j+=NTHR){
          int idx=(int)gldu(&p.cand[j]);
          float l=gldf(&p.l_ws[idx]);
          better += (l>hp || (l==hp && idx<hidx)) ? 1 : 0;
        }
        better = blockRedSum(better,tid,smi);
        if (better < KTOP){ a=hidx; fb=1; } else { a=bi; fb=-1; }
      } else { a=bi; fb=-1; }
      if (a<0 || a>=OUTN) a=0;      // safety clamp

      if (tid==0){
        p.out[t]       = (float)a;
        p.out[NSTEP+t] = (float)fb;
        atomicAnd(&p.mask_bits[a>>5], ~(1u<<(a&31)));
      }

      // LSTM update (h_l still holds this step's h from phase L)
      if (tid<HID) emb_l[tid]=p.emb[(size_t)a*HID+tid] * (float)fb;
      __syncthreads();
      float g = dot128f(p.Wih+(size_t)tid*HID, emb_l) + dot128f(p.Whh+(size_t)tid*HID, h_l)
              + p.bih[tid] + p.bhh[tid];
      gates[tid]=g;
      __syncthreads();
      if (tid<HID){
        float ig=gates[tid], fg=gates[tid+HID], gg=gates[tid+2*HID], og=gates[tid+3*HID];
        float si=1.f/(1.f+expf(-ig)), sf=1.f/(1.f+expf(-fg)), so=1.f/(1.f+expf(-og));
        float cn=sf*gldf(&p.c_ws[tid])+si*tanhf(gg);
        float hn=so*tanhf(cn);
        gstf(&p.c_ws[tid],cn); gstf(&p.h_ws[tid],hn);
      }

      if (tid==0){
        gstu(p.gcount,0u);
        float mean=gsl/2.0e5f;
        float var =gsl2/2.0e5f - mean*mean;
        float sg  =sqrtf(fmaxf(var,0.f));
        gstf(&p.rparams[0],gmx-24.f*sg);
        gstf(&p.rparams[1],(sg>0.f)?((float)NBINS/(32.f*sg)):0.f);
      }
    } else if (bid==1){
      for (int i=tid;i<NBINS;i+=NTHR) gstu(&p.hist_g[i],0u);
    }
    barT += NBLK; gsync(p.bar, barT);
  }
}

// ---------- host ----------
extern "C" void kernel_launch(void* const* d_in, const int* in_sizes, int n_in,
                              void* d_out, int out_size, void* d_ws, size_t ws_size,
                              hipStream_t stream)
{
  const int*   x    = (const int*)d_in[0];
  const float* emb  = (const float*)d_in[1];
  const float* Wih  = (const float*)d_in[2];
  const float* Whh  = (const float*)d_in[3];
  const float* bih  = (const float*)d_in[4];
  const float* bhh  = (const float*)d_in[5];
  const float* Wout = (const float*)d_in[6];
  const float* bout = (const float*)d_in[7];
  float* out = (float*)d_out;

  char* ws = (char*)d_ws;
  float*    l_ws      = (float*)(ws + 0);         // 800000 B
  float*    partials  = (float*)(ws + 800000);    // 8192
  unsigned* mask_bits = (unsigned*)(ws + 808192); // 25000 (+pad)
  unsigned* inx_bits  = (unsigned*)(ws + 833280); // 25000 (+pad)
  unsigned* hist_g    = (unsigned*)(ws + 858368); // 4096
  unsigned* cand      = (unsigned*)(ws + 862464); // 16384
  unsigned* gcount    = (unsigned*)(ws + 878848); // 4
  unsigned* bar       = (unsigned*)(ws + 878976); // 4 (own cacheline)
  float*    rparams   = (float*)(ws + 879104);    // 8 (pad 256)
  float*    h_ws      = (float*)(ws + 879360);    // 512
  float*    c_ws      = (float*)(ws + 879872);    // 512 -> total 880384 B

  hipLaunchKernelGGL(k_init, dim3(1), dim3(1024), 0, stream,
                     x, bih, bhh, mask_bits, inx_bits, hist_g, gcount, rparams, h_ws, c_ws, bar);

  FusedP p;
  p.emb=emb; p.Wih=Wih; p.Whh=Whh; p.bih=bih; p.bhh=bhh; p.Wout=Wout; p.bout=bout;
  p.out=out; p.l_ws=l_ws; p.partials=partials;
  p.mask_bits=mask_bits; p.inx_bits=inx_bits; p.hist_g=hist_g;
  p.cand=cand; p.gcount=gcount; p.rparams=rparams;
  p.h_ws=h_ws; p.c_ws=c_ws; p.bar=bar;

  void* args[] = { &p };
  hipLaunchCooperativeKernel((const void*)k_fused, dim3(NBLK), dim3(NTHR), args, 0, stream);
}